// Round 6
// baseline (7172.585 us; speedup 1.0000x reference)
//
#include <hip/hip_runtime.h>
#include <hip/hip_bf16.h>
#include <cstdint>

// ---------------------------------------------------------------------------
// BiLSTM: x[2048,1024] -> bidirectional LSTM (H=1024) -> FC to 1000 classes.
//   1. convert_all: fp32 -> f16 copies (vectorized float4 -> h2x2)
//   2. gemm_f16<0>: x_proj_d = x_d @ W_ih_d^T + b_ih + b_hh   (f16 MFMA)
//   3. lstm_rec R6: 256 blocks x 256 thr (all 256 CUs). 128 blocks/dir,
//      block owns 8 h = 32 W_hh rows. Wave wv owns jj {2wv,2wv+1}; lane =
//      [gate(2)|kq(4)]; thread = 2 rows x 64-k slice -> 64 fdot2 (halved
//      from R5), each h uint4 LDS read feeds 2 rows (per-CU LDS unchanged).
//      Post-dot all in-wave: butterfly over kq, cndmask+4shfl gate gather
//      (no LDS transpose), replicated cell, lane0 publishes 1 seq-embedded
//      u64/wave. Single barrier/step; LDS h double-buffered; xp(t+1)
//      prefetched after poll (vmcnt-FIFO safe).
//   4. gemm_f16<1>: out = h_hist @ fc_W^T + fc_b
// ---------------------------------------------------------------------------

typedef __fp16 h2 __attribute__((ext_vector_type(2)));
typedef __fp16 h8 __attribute__((ext_vector_type(8)));
typedef float f4 __attribute__((ext_vector_type(4)));
typedef unsigned long long u64;

#define T_LEN 2048

static __device__ __forceinline__ unsigned int packh2(float a, float b) {
  h2 r = __builtin_amdgcn_cvt_pkrtz(a, b);
  return __builtin_bit_cast(unsigned int, r);
}
static __device__ __forceinline__ float fdot2u(unsigned int a, unsigned int b, float c) {
  return __builtin_amdgcn_fdot2(__builtin_bit_cast(h2, a), __builtin_bit_cast(h2, b), c, false);
}
static __device__ __forceinline__ float sigmoidf_(float x) {
  return 1.f / (1.f + __expf(-x));
}
static __device__ __forceinline__ float tanhf_(float x) {
  float e = __expf(-2.f * fabsf(x));
  float r = (1.f - e) / (1.f + e);
  return copysignf(r, x);
}

// ---------------------------------------------------------------------------
// convert fp32 -> f16, 4 elements/thread (float4 in, 2 packed dwords out)
// ---------------------------------------------------------------------------
__global__ void convert_all(const float* __restrict__ x, const float* __restrict__ wf,
                            const float* __restrict__ wb, const float* __restrict__ fcw,
                            _Float16* __restrict__ xf, _Float16* __restrict__ wff,
                            _Float16* __restrict__ wbf, _Float16* __restrict__ fcwf) {
  const size_t SX = 2097152, SW = 4194304, SFC = 2097152;
  size_t i = ((size_t)blockIdx.x * 256 + threadIdx.x) * 4;
  if (i < SX) {
    float4 v = *(const float4*)(x + i);
    *(uint2*)(xf + i) = make_uint2(packh2(v.x, v.y), packh2(v.z, v.w));
  } else if (i < SX + SW) {
    size_t j = i - SX;
    float4 v = *(const float4*)(wf + j);
    *(uint2*)(wff + j) = make_uint2(packh2(v.x, v.y), packh2(v.z, v.w));
  } else if (i < SX + 2 * SW) {
    size_t j = i - SX - SW;
    float4 v = *(const float4*)(wb + j);
    *(uint2*)(wbf + j) = make_uint2(packh2(v.x, v.y), packh2(v.z, v.w));
  } else if (i < SX + 2 * SW + SFC) {
    size_t j = i - SX - 2 * SW;
    int row = (int)(j >> 11), col = (int)(j & 2047);
    float4 v = make_float4(0.f, 0.f, 0.f, 0.f);
    if (row < 1000) v = *(const float4*)(fcw + (size_t)row * 2048 + col);
    *(uint2*)(fcwf + j) = make_uint2(packh2(v.x, v.y), packh2(v.z, v.w));
  }
}

// zero the h-communication buffers: gen 0 == valid zeros for t=0
__global__ void init_state(u64* __restrict__ hc) {
  int t = threadIdx.x;
  for (int i = t; i < 2048; i += 256) hc[i] = 0ull;
}

// ---------------------------------------------------------------------------
// f16 GEMM, 128x128 tile, BK=64 (unchanged — verified R2..R5)
// ---------------------------------------------------------------------------
#define LSTR 80

template <int MODE>
__global__ __launch_bounds__(256, 2) void gemm_f16(
    const _Float16* __restrict__ A, const _Float16* __restrict__ B,
    const float* __restrict__ bias1, const float* __restrict__ bias2,
    void* __restrict__ Cout, int M, int N, int K, int nout, int rev) {
  __shared__ _Float16 As[128 * LSTR];
  __shared__ _Float16 Bs[128 * LSTR];

  const int tid = threadIdx.x;
  const int ntn = N >> 7;
  const int tm = blockIdx.x / ntn, tn = blockIdx.x % ntn;
  const int wid = tid >> 6, lane = tid & 63;
  const int wr = wid >> 1, wc = wid & 1;
  const int quad = lane >> 4, l16 = lane & 15;

  const int srow = tid >> 1, seg = tid & 1;
  const int arow = rev ? (M - 1 - (tm * 128 + srow)) : (tm * 128 + srow);
  const int brow = tn * 128 + srow;

  f4 acc[4][4];
#pragma unroll
  for (int i = 0; i < 4; ++i)
#pragma unroll
    for (int j = 0; j < 4; ++j) acc[i][j] = (f4)0.f;

  for (int k0 = 0; k0 < K; k0 += 64) {
    uint4 va[4], vb[4];
    const uint4* gpa = (const uint4*)(A + (size_t)arow * K + k0 + seg * 32);
    const uint4* gpb = (const uint4*)(B + (size_t)brow * K + k0 + seg * 32);
#pragma unroll
    for (int c = 0; c < 4; ++c) va[c] = gpa[c];
#pragma unroll
    for (int c = 0; c < 4; ++c) vb[c] = gpb[c];

    __syncthreads();
    uint4* lpa = (uint4*)&As[srow * LSTR + seg * 32];
    uint4* lpb = (uint4*)&Bs[srow * LSTR + seg * 32];
#pragma unroll
    for (int c = 0; c < 4; ++c) lpa[c] = va[c];
#pragma unroll
    for (int c = 0; c < 4; ++c) lpb[c] = vb[c];
    __syncthreads();

#pragma unroll
    for (int kk = 0; kk < 64; kk += 32) {
      h8 af[4], bf[4];
#pragma unroll
      for (int i = 0; i < 4; ++i) {
        int m = wr * 64 + i * 16 + l16;
        af[i] = *(const h8*)&As[m * LSTR + kk + quad * 8];
        int n = wc * 64 + i * 16 + l16;
        bf[i] = *(const h8*)&Bs[n * LSTR + kk + quad * 8];
      }
#pragma unroll
      for (int i = 0; i < 4; ++i)
#pragma unroll
        for (int j = 0; j < 4; ++j)
          acc[i][j] = __builtin_amdgcn_mfma_f32_16x16x32_f16(af[i], bf[j], acc[i][j], 0, 0, 0);
    }
  }

  const int cm0 = tm * 128 + wr * 64, cn0 = tn * 128 + wc * 64;
#pragma unroll
  for (int i = 0; i < 4; ++i) {
#pragma unroll
    for (int j = 0; j < 4; ++j) {
      int n = cn0 + j * 16 + l16;
#pragma unroll
      for (int r = 0; r < 4; ++r) {
        int m = cm0 + i * 16 + quad * 4 + r;
        float v = acc[i][j][r];
        if (MODE == 0) {
          v += bias1[n] + bias2[n];
          ((_Float16*)Cout)[(size_t)m * N + n] = (_Float16)v;
        } else {
          if (n < nout) ((float*)Cout)[(size_t)m * nout + n] = v + bias1[n];
        }
      }
    }
  }
}

// ---------------------------------------------------------------------------
// Persistent BiLSTM recurrence, R6.
// 256 blocks x 256 thr. blk>>7 = dir, ib = blk&127, block owns 8 h
// (j0=ib*8 .. +7) = 32 W_hh rows. Wave wv owns jj {2wv,2wv+1}; lane l:
// gate g=l>>4, kq=l&15, q=l&1. Thread rows: wrow0=g*1024+j0+2wv (+0,1),
// k-slice kq*64..+63 (shared by both rows).
// hc: [buf][dir][512] u64; word w = [h2(h[2w],h[2w+1]) | seq32].
// Consumer of step t polls buf t&1 words {2tid,2tid+1} for seq==t (whole
// direction covered by the block -> barrier); producer wave stores word
// ib*4+wv with seq=t+1 into buf (t+1)&1. 2-buffer safety: publishing t+1
// data-depends on having observed ALL of gen t, so gen t-1's slot is dead.
// LDS h: double-buffered, 16 segs x 36 dwords (pad -> max 2-way, free).
// ---------------------------------------------------------------------------
__global__ __launch_bounds__(256, 1) void lstm_rec(
    const float* __restrict__ Whh_f, const float* __restrict__ Whh_b,
    const _Float16* __restrict__ xp,   // [2][2048][4096]
    u64* __restrict__ hc,              // [2][2][512]
    _Float16* __restrict__ hhist) {    // [2048][2048]
  const int tid = threadIdx.x;
  const int blk = blockIdx.x;
  const int dir = blk >> 7;
  const int ib = blk & 127;
  const int j0 = ib * 8;
  const int wv = tid >> 6;
  const int l = tid & 63;
  const int g = l >> 4;      // gate 0..3 (i,f,g,o)
  const int kq = l & 15;     // 16 k-slices of 64
  const int q = l & 1;       // cell-replica jj index (0/1)
  const int wrow0 = g * 1024 + j0 + 2 * wv;

  const float* Whh = dir ? Whh_b : Whh_f;
  const _Float16* xpd = xp + (size_t)dir * (2048u * 4096u);

  __shared__ unsigned int lds_h[2][16 * 36];  // [buf][seg stride 36]

  // one-time: W_hh[wrow0+r][kq*64 .. +63] -> f16 regs (2 rows x 32 dwords)
  unsigned int w[2][32];
#pragma unroll
  for (int r = 0; r < 2; ++r) {
    const float* wp = Whh + (size_t)(wrow0 + r) * 1024 + kq * 64;
#pragma unroll
    for (int i = 0; i < 16; ++i) {
      float4 v = ((const float4*)wp)[i];
      w[r][2 * i] = packh2(v.x, v.y);
      w[r][2 * i + 1] = packh2(v.z, v.w);
    }
  }

  float c = 0.f;  // cell state for jj=2wv+q (replicated across 32 lanes)

  // x_proj for t=0: rows wrow0, wrow0+1 = 2 consecutive f16 = 1 dword
  unsigned xv = *(const unsigned*)(xpd + wrow0);
  h2 xh = __builtin_bit_cast(h2, xv);
  float xf0 = (float)xh[0], xf1 = (float)xh[1];

  for (int t = 0; t < T_LEN; ++t) {
    const int buf = t & 1;
    // ---- poll own 2 words (widx = 2tid, 2tid+1; contiguous 16B) ----
    unsigned d0, d1;
    {
      u64* src = hc + (((size_t)buf * 2 + dir) * 512 + 2 * tid);
      u64 a = __hip_atomic_load(&src[0], __ATOMIC_RELAXED, __HIP_MEMORY_SCOPE_AGENT);
      u64 b = __hip_atomic_load(&src[1], __ATOMIC_RELAXED, __HIP_MEMORY_SCOPE_AGENT);
      int cnt = 0;
      while ((unsigned)a != (unsigned)t || (unsigned)b != (unsigned)t) {
        if (++cnt > (1 << 12)) break;  // bailout: fail absmax, never hang
        a = __hip_atomic_load(&src[0], __ATOMIC_RELAXED, __HIP_MEMORY_SCOPE_AGENT);
        b = __hip_atomic_load(&src[1], __ATOMIC_RELAXED, __HIP_MEMORY_SCOPE_AGENT);
      }
      d0 = (unsigned)(a >> 32);
      d1 = (unsigned)(b >> 32);
    }

    // prefetch NEXT step's x_proj (after poll loads -> off the vmcnt path)
    int tnx = (t + 1 < T_LEN) ? t + 1 : t;
    unsigned xn = *(const unsigned*)(xpd + (size_t)tnx * 4096 + wrow0);

    // stage h payload: dwords 2tid,2tid+1 -> seg tid>>4, offset 2*(tid&15)
    *(uint2*)&lds_h[buf][(tid >> 4) * 36 + 2 * (tid & 15)] = make_uint2(d0, d1);
    __syncthreads();  // single barrier per step

    // ---- dot: 2 rows x 64-elem slice; 8 ds_read_b128, 64 fdot2 ----
    float acc0 = 0.f, acc1 = 0.f;
    const uint4* hp = (const uint4*)&lds_h[buf][kq * 36];
#pragma unroll
    for (int i = 0; i < 8; ++i) {
      uint4 hv = hp[i];
      acc0 = fdot2u(w[0][4 * i + 0], hv.x, acc0);
      acc0 = fdot2u(w[0][4 * i + 1], hv.y, acc0);
      acc0 = fdot2u(w[0][4 * i + 2], hv.z, acc0);
      acc0 = fdot2u(w[0][4 * i + 3], hv.w, acc0);
      acc1 = fdot2u(w[1][4 * i + 0], hv.x, acc1);
      acc1 = fdot2u(w[1][4 * i + 1], hv.y, acc1);
      acc1 = fdot2u(w[1][4 * i + 2], hv.z, acc1);
      acc1 = fdot2u(w[1][4 * i + 3], hv.w, acc1);
    }
    // butterfly reduce over kq (lane bits 0..3); all lanes get both sums
#pragma unroll
    for (int m = 1; m < 16; m <<= 1) {
      acc0 += __shfl_xor(acc0, m, 64);
      acc1 += __shfl_xor(acc1, m, 64);
    }

    // in-wave gate gather: lane j*16+q holds preact (gate j, jj=2wv+q)
    float val = (q ? acc1 + xf1 : acc0 + xf0);
    float pi = __shfl(val, 0 + q, 64);
    float pf = __shfl(val, 16 + q, 64);
    float pg = __shfl(val, 32 + q, 64);
    float po = __shfl(val, 48 + q, 64);

    float ii = sigmoidf_(pi);
    float ff = sigmoidf_(pf);
    float g_ = tanhf_(pg);
    float oo = sigmoidf_(po);
    c = ff * c + ii * g_;
    float h = oo * tanhf_(c);  // h for jj=2wv+q

    // lane0 packs (h@q0, h@q1) and publishes the wave's word
    float h1 = __shfl(h, 1, 64);
    if (l == 0) {
      unsigned hh = packh2(h, h1);
      u64 word = ((u64)hh << 32) | (unsigned)(t + 1);
      u64* dst = hc + (((size_t)((t + 1) & 1) * 2 + dir) * 512 + (ib * 4 + wv));
      __hip_atomic_store(dst, word, __ATOMIC_RELAXED, __HIP_MEMORY_SCOPE_AGENT);
      // hhist AFTER publish: off the critical sync path
      int tout = dir ? (T_LEN - 1 - t) : t;
      *(unsigned*)&hhist[(size_t)tout * 2048 + dir * 1024 + j0 + 2 * wv] = hh;
    }

    // convert next-step xp (prefetched above)
    xh = __builtin_bit_cast(h2, xn);
    xf0 = (float)xh[0];
    xf1 = (float)xh[1];
  }
}

// ---------------------------------------------------------------------------
extern "C" void kernel_launch(void* const* d_in, const int* in_sizes, int n_in,
                              void* d_out, int out_size, void* d_ws, size_t ws_size,
                              hipStream_t stream) {
  (void)in_sizes; (void)n_in; (void)out_size; (void)ws_size;
  const float* x     = (const float*)d_in[0];
  const float* Wih_f = (const float*)d_in[1];
  const float* Whh_f = (const float*)d_in[2];
  const float* bih_f = (const float*)d_in[3];
  const float* bhh_f = (const float*)d_in[4];
  const float* Wih_b = (const float*)d_in[5];
  const float* Whh_b = (const float*)d_in[6];
  const float* bih_b = (const float*)d_in[7];
  const float* bhh_b = (const float*)d_in[8];
  const float* fcW   = (const float*)d_in[9];
  const float* fcb   = (const float*)d_in[10];

  char* ws = (char*)d_ws;
  _Float16* xf16   = (_Float16*)(ws + 0);
  _Float16* wih16f = (_Float16*)(ws + 4194304);
  _Float16* wih16b = (_Float16*)(ws + 12582912);
  _Float16* fcw16  = (_Float16*)(ws + 20971520);
  _Float16* xp16   = (_Float16*)(ws + 25165824);   // [2][2048][4096]
  _Float16* hhist  = (_Float16*)(ws + 58720256);   // [2048][2048]
  u64*      hc     = (u64*)     (ws + 67108864);   // [2][2][512]

  const size_t SX = 2097152, SW = 4194304, SFC = 2097152;
  const size_t total_cvt = SX + 2 * SW + SFC;

  convert_all<<<dim3((unsigned)(total_cvt / 4 / 256)), 256, 0, stream>>>(
      x, Wih_f, Wih_b, fcW, xf16, wih16f, wih16b, fcw16);
  init_state<<<1, 256, 0, stream>>>(hc);

  gemm_f16<0><<<dim3(512), 256, 0, stream>>>(xf16, wih16f, bih_f, bhh_f,
                                             (void*)xp16, 2048, 4096, 1024, 4096, 0);
  gemm_f16<0><<<dim3(512), 256, 0, stream>>>(xf16, wih16b, bih_b, bhh_b,
                                             (void*)(xp16 + (size_t)2048 * 4096),
                                             2048, 4096, 1024, 4096, 1);

  lstm_rec<<<dim3(256), 256, 0, stream>>>(Whh_f, Whh_b, xp16, hc, hhist);

  gemm_f16<1><<<dim3(128), 256, 0, stream>>>(hhist, fcw16, fcb, nullptr,
                                             d_out, 2048, 1024, 2048, 1000, 0);
}

// Round 9
// 4280.547 us; speedup vs baseline: 1.6756x; 1.6756x over previous
//
#include <hip/hip_runtime.h>
#include <hip/hip_bf16.h>
#include <cstdint>

// ---------------------------------------------------------------------------
// BiLSTM: x[2048,1024] -> bidirectional LSTM (H=1024) -> FC to 1000 classes.
//   1. convert_all: fp32 -> f16 copies (vectorized float4 -> h2x2)
//   2. gemm_f16<0>: BOTH x_proj GEMMs in one 1024-block launch (dir = blk&1)
//   3. lstm_rec R9 = R5 (proven: 64 blk/dir x 256 thr, 16 h/block, 4-row LDS
//      reuse, in-wave cell, agent-scope seq-embedded u64 publish) + PIPELINED
//      POLL: 4-deep ring of independent load pairs (8 loads in flight; FIFO
//      vmcnt -> each check waits only the oldest pair). R5's serial poll
//      waited a full LLC round trip (~450ns) per sample -> expected observe
//      delay ~1.5*RT; the ring samples every ~RT/4 -> saves ~300-450ns/step.
//   4. gemm_f16<1>: out = h_hist @ fc_W^T + fc_b
// Lessons: R4 (LDS read must feed 4 rows), R6 (64 blocks/dir, not more),
// R8 (sc0 cross-CU publish unreliable -> stay with agent-scope atomics).
// ---------------------------------------------------------------------------

typedef __fp16 h2 __attribute__((ext_vector_type(2)));
typedef __fp16 h8 __attribute__((ext_vector_type(8)));
typedef float f4 __attribute__((ext_vector_type(4)));
typedef unsigned long long u64;

#define T_LEN 2048

static __device__ __forceinline__ unsigned int packh2(float a, float b) {
  h2 r = __builtin_amdgcn_cvt_pkrtz(a, b);
  return __builtin_bit_cast(unsigned int, r);
}
static __device__ __forceinline__ float fdot2u(unsigned int a, unsigned int b, float c) {
  return __builtin_amdgcn_fdot2(__builtin_bit_cast(h2, a), __builtin_bit_cast(h2, b), c, false);
}
static __device__ __forceinline__ float sigmoidf_(float x) {
  return 1.f / (1.f + __expf(-x));
}
static __device__ __forceinline__ float tanhf_(float x) {
  float e = __expf(-2.f * fabsf(x));
  float r = (1.f - e) / (1.f + e);
  return copysignf(r, x);
}
static __device__ __forceinline__ u64 ld_agent(const u64* p) {
  return __hip_atomic_load(p, __ATOMIC_RELAXED, __HIP_MEMORY_SCOPE_AGENT);
}

// ---------------------------------------------------------------------------
// convert fp32 -> f16, 4 elements/thread
// ---------------------------------------------------------------------------
__global__ void convert_all(const float* __restrict__ x, const float* __restrict__ wf,
                            const float* __restrict__ wb, const float* __restrict__ fcw,
                            _Float16* __restrict__ xf, _Float16* __restrict__ wff,
                            _Float16* __restrict__ wbf, _Float16* __restrict__ fcwf) {
  const size_t SX = 2097152, SW = 4194304, SFC = 2097152;
  size_t i = ((size_t)blockIdx.x * 256 + threadIdx.x) * 4;
  if (i < SX) {
    float4 v = *(const float4*)(x + i);
    *(uint2*)(xf + i) = make_uint2(packh2(v.x, v.y), packh2(v.z, v.w));
  } else if (i < SX + SW) {
    size_t j = i - SX;
    float4 v = *(const float4*)(wf + j);
    *(uint2*)(wff + j) = make_uint2(packh2(v.x, v.y), packh2(v.z, v.w));
  } else if (i < SX + 2 * SW) {
    size_t j = i - SX - SW;
    float4 v = *(const float4*)(wb + j);
    *(uint2*)(wbf + j) = make_uint2(packh2(v.x, v.y), packh2(v.z, v.w));
  } else if (i < SX + 2 * SW + SFC) {
    size_t j = i - SX - 2 * SW;
    int row = (int)(j >> 11), col = (int)(j & 2047);
    float4 v = make_float4(0.f, 0.f, 0.f, 0.f);
    if (row < 1000) v = *(const float4*)(fcw + (size_t)row * 2048 + col);
    *(uint2*)(fcwf + j) = make_uint2(packh2(v.x, v.y), packh2(v.z, v.w));
  }
}

// zero the h-communication buffers: gen 0 == valid zeros for t=0
__global__ void init_state(u64* __restrict__ hc) {
  int t = threadIdx.x;
  for (int i = t; i < 2048; i += 256) hc[i] = 0ull;
}

// ---------------------------------------------------------------------------
// f16 GEMM, 128x128 tile, BK=64.
// MODE 0: both proj GEMMs in one launch; dir = blk&1 (dir1: reversed A rows,
//         weights/biases _b, output offset by M*N). f16 out.
// MODE 1: fc, fp32 out, store guard n<nout.
// ---------------------------------------------------------------------------
#define LSTR 80

template <int MODE>
__global__ __launch_bounds__(256, 2) void gemm_f16(
    const _Float16* __restrict__ A, const _Float16* __restrict__ Bf,
    const _Float16* __restrict__ Bb,
    const float* __restrict__ b1f, const float* __restrict__ b2f,
    const float* __restrict__ b1b, const float* __restrict__ b2b,
    void* __restrict__ Cout, int M, int N, int K, int nout) {
  __shared__ _Float16 As[128 * LSTR];
  __shared__ _Float16 Bs[128 * LSTR];

  int bid, dirv;
  const _Float16* B;
  const float* bias1;
  const float* bias2;
  if (MODE == 0) {
    dirv = blockIdx.x & 1;
    bid = blockIdx.x >> 1;
    B = dirv ? Bb : Bf;
    bias1 = dirv ? b1b : b1f;
    bias2 = dirv ? b2b : b2f;
  } else {
    dirv = 0;
    bid = blockIdx.x;
    B = Bf;
    bias1 = b1f;
    bias2 = nullptr;
  }
  const int rev = (MODE == 0) ? dirv : 0;

  const int tid = threadIdx.x;
  const int ntn = N >> 7;
  const int tm = bid / ntn, tn = bid % ntn;
  const int wid = tid >> 6, lane = tid & 63;
  const int wr = wid >> 1, wc = wid & 1;
  const int quad = lane >> 4, l16 = lane & 15;

  const int srow = tid >> 1, seg = tid & 1;
  const int arow = rev ? (M - 1 - (tm * 128 + srow)) : (tm * 128 + srow);
  const int brow = tn * 128 + srow;

  f4 acc[4][4];
#pragma unroll
  for (int i = 0; i < 4; ++i)
#pragma unroll
    for (int j = 0; j < 4; ++j) acc[i][j] = (f4)0.f;

  for (int k0 = 0; k0 < K; k0 += 64) {
    uint4 va[4], vb[4];
    const uint4* gpa = (const uint4*)(A + (size_t)arow * K + k0 + seg * 32);
    const uint4* gpb = (const uint4*)(B + (size_t)brow * K + k0 + seg * 32);
#pragma unroll
    for (int c = 0; c < 4; ++c) va[c] = gpa[c];
#pragma unroll
    for (int c = 0; c < 4; ++c) vb[c] = gpb[c];

    __syncthreads();
    uint4* lpa = (uint4*)&As[srow * LSTR + seg * 32];
    uint4* lpb = (uint4*)&Bs[srow * LSTR + seg * 32];
#pragma unroll
    for (int c = 0; c < 4; ++c) lpa[c] = va[c];
#pragma unroll
    for (int c = 0; c < 4; ++c) lpb[c] = vb[c];
    __syncthreads();

#pragma unroll
    for (int kk = 0; kk < 64; kk += 32) {
      h8 af[4], bf[4];
#pragma unroll
      for (int i = 0; i < 4; ++i) {
        int m = wr * 64 + i * 16 + l16;
        af[i] = *(const h8*)&As[m * LSTR + kk + quad * 8];
        int n = wc * 64 + i * 16 + l16;
        bf[i] = *(const h8*)&Bs[n * LSTR + kk + quad * 8];
      }
#pragma unroll
      for (int i = 0; i < 4; ++i)
#pragma unroll
        for (int j = 0; j < 4; ++j)
          acc[i][j] = __builtin_amdgcn_mfma_f32_16x16x32_f16(af[i], bf[j], acc[i][j], 0, 0, 0);
    }
  }

  const int cm0 = tm * 128 + wr * 64, cn0 = tn * 128 + wc * 64;
#pragma unroll
  for (int i = 0; i < 4; ++i) {
#pragma unroll
    for (int j = 0; j < 4; ++j) {
      int n = cn0 + j * 16 + l16;
#pragma unroll
      for (int r = 0; r < 4; ++r) {
        int m = cm0 + i * 16 + quad * 4 + r;
        float v = acc[i][j][r];
        if (MODE == 0) {
          v += bias1[n] + bias2[n];
          ((_Float16*)Cout)[(size_t)dirv * M * N + (size_t)m * N + n] = (_Float16)v;
        } else {
          if (n < nout) ((float*)Cout)[(size_t)m * nout + n] = v + bias1[n];
        }
      }
    }
  }
}

// ---------------------------------------------------------------------------
// Persistent BiLSTM recurrence, R9 = R5 + pipelined poll ring.
// 128 blocks x 256 thr (4 waves). blk<64 fwd else bwd. Block owns 16 h
// (j0..j0+15) = 64 W_hh rows. Wave wv owns jj {4wv..4wv+3}, lane l:
// gate g=l>>4, kq=l&15, q=l&3. Thread rows: wrow0=g*1024+j0+4wv (+0..3),
// k-slice kq*64..+63 (shared by 4 rows -> LDS-efficient dot).
// hc: [buf][dir][512] u64; word w = [h2(h[2w],h[2w+1]) | seq32].
// Poll ring: 4 slots x (2 loads); 8 loads in flight; FIFO vmcnt means each
// slot check waits only the oldest pair -> sampling period ~RT/4.
// ---------------------------------------------------------------------------
__global__ __launch_bounds__(256, 1) void lstm_rec(
    const float* __restrict__ Whh_f, const float* __restrict__ Whh_b,
    const _Float16* __restrict__ xp,   // [2][2048][4096]
    u64* __restrict__ hc,              // [2][2][512]
    _Float16* __restrict__ hhist) {    // [2048][2048]
  const int tid = threadIdx.x;
  const int blk = blockIdx.x;
  const int dir = blk >> 6;
  const int ib = blk & 63;
  const int j0 = ib * 16;
  const int wv = tid >> 6;
  const int l = tid & 63;
  const int g = l >> 4;      // gate 0..3 (i,f,g,o)
  const int kq = l & 15;     // 16 k-slices of 64
  const int q = l & 3;       // cell-replica jj index
  const int wrow0 = g * 1024 + j0 + 4 * wv;

  const float* Whh = dir ? Whh_b : Whh_f;
  const _Float16* xpd = xp + (size_t)dir * (2048u * 4096u);

  __shared__ unsigned int lds_h[2][16 * 36];  // [buf][seg stride 36]
  __shared__ float lds_tr[4 * 16];            // per-wave gate transpose

  // one-time: W_hh[wrow0+j][kq*64 .. +63] -> f16 regs (4 rows x 32 dwords)
  unsigned int w[4][32];
#pragma unroll
  for (int j = 0; j < 4; ++j) {
    const float* wp = Whh + (size_t)(wrow0 + j) * 1024 + kq * 64;
#pragma unroll
    for (int i = 0; i < 16; ++i) {
      float4 v = ((const float4*)wp)[i];
      w[j][2 * i] = packh2(v.x, v.y);
      w[j][2 * i + 1] = packh2(v.z, v.w);
    }
  }

  float c = 0.f;  // cell state for jj=4wv+q (replicated across 16 lanes)

  // x_proj for t=0 (4 consecutive f16 at wrow0)
  uint2 xv = *(const uint2*)(xpd + wrow0);
  h2 x01 = __builtin_bit_cast(h2, xv.x);
  h2 x23 = __builtin_bit_cast(h2, xv.y);
  float xf[4] = {(float)x01[0], (float)x01[1], (float)x23[0], (float)x23[1]};

  for (int t = 0; t < T_LEN; ++t) {
    const int buf = t & 1;
    // ---- pipelined poll of own 2 words (2tid, 2tid+1) ----
    unsigned d0, d1;
    {
      const u64* src = hc + (((size_t)buf * 2 + dir) * 512 + 2 * tid);
      const unsigned tt = (unsigned)t;
      // fill 4-deep ring (8 independent loads in flight)
      u64 a0 = ld_agent(&src[0]), b0 = ld_agent(&src[1]);
      u64 a1 = ld_agent(&src[0]), b1 = ld_agent(&src[1]);
      u64 a2 = ld_agent(&src[0]), b2 = ld_agent(&src[1]);
      u64 a3 = ld_agent(&src[0]), b3 = ld_agent(&src[1]);
      int cnt = 0;
      while (true) {
        if ((unsigned)a0 == tt && (unsigned)b0 == tt) { d0 = (unsigned)(a0 >> 32); d1 = (unsigned)(b0 >> 32); break; }
        a0 = ld_agent(&src[0]); b0 = ld_agent(&src[1]);
        if ((unsigned)a1 == tt && (unsigned)b1 == tt) { d0 = (unsigned)(a1 >> 32); d1 = (unsigned)(b1 >> 32); break; }
        a1 = ld_agent(&src[0]); b1 = ld_agent(&src[1]);
        if ((unsigned)a2 == tt && (unsigned)b2 == tt) { d0 = (unsigned)(a2 >> 32); d1 = (unsigned)(b2 >> 32); break; }
        a2 = ld_agent(&src[0]); b2 = ld_agent(&src[1]);
        if ((unsigned)a3 == tt && (unsigned)b3 == tt) { d0 = (unsigned)(a3 >> 32); d1 = (unsigned)(b3 >> 32); break; }
        a3 = ld_agent(&src[0]); b3 = ld_agent(&src[1]);
        if (++cnt > (1 << 11)) { d0 = (unsigned)(a0 >> 32); d1 = (unsigned)(b0 >> 32); break; }  // no-hang bailout
      }
    }

    // prefetch NEXT step's x_proj (after poll loads -> off the vmcnt path)
    int tnx = (t + 1 < T_LEN) ? t + 1 : t;
    uint2 xn = *(const uint2*)(xpd + (size_t)tnx * 4096 + wrow0);

    // stage h payload: dwords 2tid,2tid+1 -> seg tid>>4, offset 2*(tid&15)
    *(uint2*)&lds_h[buf][(tid >> 4) * 36 + 2 * (tid & 15)] = make_uint2(d0, d1);
    __syncthreads();  // single barrier per step

    // ---- dot: 4 rows x 64-elem slice; 8 ds_read_b128, 128 fdot2 ----
    float acc0 = 0.f, acc1 = 0.f, acc2 = 0.f, acc3 = 0.f;
    const uint4* hp = (const uint4*)&lds_h[buf][kq * 36];
#pragma unroll
    for (int i = 0; i < 8; ++i) {
      uint4 hv = hp[i];
      acc0 = fdot2u(w[0][4 * i + 0], hv.x, acc0);
      acc0 = fdot2u(w[0][4 * i + 1], hv.y, acc0);
      acc0 = fdot2u(w[0][4 * i + 2], hv.z, acc0);
      acc0 = fdot2u(w[0][4 * i + 3], hv.w, acc0);
      acc1 = fdot2u(w[1][4 * i + 0], hv.x, acc1);
      acc1 = fdot2u(w[1][4 * i + 1], hv.y, acc1);
      acc1 = fdot2u(w[1][4 * i + 2], hv.z, acc1);
      acc1 = fdot2u(w[1][4 * i + 3], hv.w, acc1);
      acc2 = fdot2u(w[2][4 * i + 0], hv.x, acc2);
      acc2 = fdot2u(w[2][4 * i + 1], hv.y, acc2);
      acc2 = fdot2u(w[2][4 * i + 2], hv.z, acc2);
      acc2 = fdot2u(w[2][4 * i + 3], hv.w, acc2);
      acc3 = fdot2u(w[3][4 * i + 0], hv.x, acc3);
      acc3 = fdot2u(w[3][4 * i + 1], hv.y, acc3);
      acc3 = fdot2u(w[3][4 * i + 2], hv.z, acc3);
      acc3 = fdot2u(w[3][4 * i + 3], hv.w, acc3);
    }
    // butterfly reduce over kq (lane bits 0..3); all lanes get group sums
#pragma unroll
    for (int m = 1; m < 16; m <<= 1) {
      acc0 += __shfl_xor(acc0, m, 64);
      acc1 += __shfl_xor(acc1, m, 64);
      acc2 += __shfl_xor(acc2, m, 64);
      acc3 += __shfl_xor(acc3, m, 64);
    }

    // in-wave transpose: lane (g,kq==0) writes 4 gate-preacts for jj 4wv+0..3
    if (kq == 0) {
      f4 v = {acc0 + xf[0], acc1 + xf[1], acc2 + xf[2], acc3 + xf[3]};
      *(f4*)&lds_tr[wv * 16 + g * 4] = v;
    }
    // same-wave LDS RAW: compiler inserts lgkmcnt wait; no barrier needed
    float pi = lds_tr[wv * 16 + 0 + q];
    float pf = lds_tr[wv * 16 + 4 + q];
    float pg = lds_tr[wv * 16 + 8 + q];
    float po = lds_tr[wv * 16 + 12 + q];

    float ii = sigmoidf_(pi);
    float ff = sigmoidf_(pf);
    float g_ = tanhf_(pg);
    float oo = sigmoidf_(po);
    c = ff * c + ii * g_;
    float h = oo * tanhf_(c);  // h for jj=4wv+q (replicated over 16 lanes)

    // lane0 gathers the wave's 4 h and publishes 2 contiguous u64 words
    float h1 = __shfl(h, 1, 64);
    float h2v = __shfl(h, 2, 64);
    float h3 = __shfl(h, 3, 64);
    if (l == 0) {
      unsigned p01 = packh2(h, h1);
      unsigned p23 = packh2(h2v, h3);
      u64 w0 = ((u64)p01 << 32) | (unsigned)(t + 1);
      u64 w1 = ((u64)p23 << 32) | (unsigned)(t + 1);
      u64* dst = hc + (((size_t)((t + 1) & 1) * 2 + dir) * 512 + (ib * 8 + 2 * wv));
      __hip_atomic_store(&dst[0], w0, __ATOMIC_RELAXED, __HIP_MEMORY_SCOPE_AGENT);
      __hip_atomic_store(&dst[1], w1, __ATOMIC_RELAXED, __HIP_MEMORY_SCOPE_AGENT);
      // hhist AFTER publish: off the critical sync path
      int tout = dir ? (T_LEN - 1 - t) : t;
      *(uint2*)&hhist[(size_t)tout * 2048 + dir * 1024 + j0 + 4 * wv] =
          make_uint2(p01, p23);
    }

    // convert next-step xp (prefetched above)
    x01 = __builtin_bit_cast(h2, xn.x);
    x23 = __builtin_bit_cast(h2, xn.y);
    xf[0] = (float)x01[0]; xf[1] = (float)x01[1];
    xf[2] = (float)x23[0]; xf[3] = (float)x23[1];
  }
}

// ---------------------------------------------------------------------------
extern "C" void kernel_launch(void* const* d_in, const int* in_sizes, int n_in,
                              void* d_out, int out_size, void* d_ws, size_t ws_size,
                              hipStream_t stream) {
  (void)in_sizes; (void)n_in; (void)out_size; (void)ws_size;
  const float* x     = (const float*)d_in[0];
  const float* Wih_f = (const float*)d_in[1];
  const float* Whh_f = (const float*)d_in[2];
  const float* bih_f = (const float*)d_in[3];
  const float* bhh_f = (const float*)d_in[4];
  const float* Wih_b = (const float*)d_in[5];
  const float* Whh_b = (const float*)d_in[6];
  const float* bih_b = (const float*)d_in[7];
  const float* bhh_b = (const float*)d_in[8];
  const float* fcW   = (const float*)d_in[9];
  const float* fcb   = (const float*)d_in[10];

  char* ws = (char*)d_ws;
  _Float16* xf16   = (_Float16*)(ws + 0);
  _Float16* wih16f = (_Float16*)(ws + 4194304);
  _Float16* wih16b = (_Float16*)(ws + 12582912);
  _Float16* fcw16  = (_Float16*)(ws + 20971520);
  _Float16* xp16   = (_Float16*)(ws + 25165824);   // [2][2048][4096]
  _Float16* hhist  = (_Float16*)(ws + 58720256);   // [2048][2048]
  u64*      hc     = (u64*)     (ws + 67108864);   // [2][2][512] (16 KB)

  const size_t SX = 2097152, SW = 4194304, SFC = 2097152;
  const size_t total_cvt = SX + 2 * SW + SFC;

  convert_all<<<dim3((unsigned)(total_cvt / 4 / 256)), 256, 0, stream>>>(
      x, Wih_f, Wih_b, fcW, xf16, wih16f, wih16b, fcw16);
  init_state<<<1, 256, 0, stream>>>(hc);

  // both proj GEMMs in one full-device launch: 2 dirs x 512 tiles
  gemm_f16<0><<<dim3(1024), 256, 0, stream>>>(
      xf16, wih16f, wih16b, bih_f, bhh_f, bih_b, bhh_b,
      (void*)xp16, 2048, 4096, 1024, 4096);

  lstm_rec<<<dim3(128), 256, 0, stream>>>(Whh_f, Whh_b, xp16, hc, hhist);

  gemm_f16<1><<<dim3(128), 256, 0, stream>>>(
      hhist, fcw16, nullptr, fcb, nullptr, nullptr, nullptr,
      d_out, 2048, 1024, 2048, 1000);
}